// Round 14
// baseline (701.161 us; speedup 1.0000x reference)
//
#include <hip/hip_runtime.h>
#include <hip/hip_bf16.h>
#include <math.h>

#define BB 2
#define TT 1024
#define CC 2048
#define HH 32
#define KK 64
#define BTROWS (BB*TT)
#define FFD 7168
#define LCH 64
#define NCH (TT/LCH)

typedef unsigned short ushort_t;
typedef __bf16 bf16x8 __attribute__((ext_vector_type(8)));
typedef float f32x4 __attribute__((ext_vector_type(4)));

__device__ __forceinline__ ushort_t f2bf(float f) {
  unsigned int u = __float_as_uint(f);
  u += 0x7fff + ((u >> 16) & 1);
  return (ushort_t)(u >> 16);
}

__device__ __forceinline__ float b2f(ushort_t b) {
  return __uint_as_float(((unsigned int)b) << 16);
}

__device__ __forceinline__ void gload16(const ushort_t* g, ushort_t* l) {
  __builtin_amdgcn_global_load_lds(
      (const __attribute__((address_space(1))) void*)g,
      (__attribute__((address_space(3))) void*)l, 16, 0, 0);
}

#define FMA4(a, s, b) { (a).x = fmaf((s), (b).x, (a).x); (a).y = fmaf((s), (b).y, (a).y); \
                        (a).z = fmaf((s), (b).z, (a).z); (a).w = fmaf((s), (b).w, (a).w); }

// ---------------------------------------------------------------- fp32 -> bf16
__global__ __launch_bounds__(256) void cvt_kernel(
    const float* __restrict__ in, ushort_t* __restrict__ out, int n4) {
  int i = blockIdx.x * 256 + threadIdx.x;
  int stride = gridDim.x * 256;
  for (; i < n4; i += stride) {
    float4 v = ((const float4*)in)[i];
    ushort4 o;
    o.x = f2bf(v.x); o.y = f2bf(v.y); o.z = f2bf(v.z); o.w = f2bf(v.w);
    ((ushort4*)out)[i] = o;
  }
}

// batched: 5 weights of CC*CC each, z selects
struct Cvt5Args {
  const float* in[5];
  ushort_t* out[5];
};

__global__ __launch_bounds__(256) void cvt5_kernel(Cvt5Args args) {
  const int z = blockIdx.y;
  const float* in = args.in[z];
  ushort_t* out = args.out[z];
  const int n4 = CC * CC / 4;
  int i = blockIdx.x * 256 + threadIdx.x;
  int stride = gridDim.x * 256;
  for (; i < n4; i += stride) {
    float4 v = ((const float4*)in)[i];
    ushort4 o;
    o.x = f2bf(v.x); o.y = f2bf(v.y); o.z = f2bf(v.z); o.w = f2bf(v.w);
    ((ushort4*)out)[i] = o;
  }
}

// ---------------------------------------------------------------- LayerNorm
__global__ __launch_bounds__(256) void ln_kernel(
    const float* __restrict__ x, const float* __restrict__ w,
    const float* __restrict__ b, float* __restrict__ out,
    float* __restrict__ last_out) {
  int row = blockIdx.x;
  const float* xr = x + (size_t)row * CC;
  float vals[8];
  float sum = 0.f, sq = 0.f;
#pragma unroll
  for (int i = 0; i < 8; ++i) {
    float v = xr[threadIdx.x + 256 * i];
    vals[i] = v; sum += v; sq += v * v;
  }
#pragma unroll
  for (int off = 32; off; off >>= 1) {
    sum += __shfl_xor(sum, off);
    sq  += __shfl_xor(sq, off);
  }
  __shared__ float red[2][4];
  int lane = threadIdx.x & 63, wv = threadIdx.x >> 6;
  if (lane == 0) { red[0][wv] = sum; red[1][wv] = sq; }
  __syncthreads();
  sum = red[0][0] + red[0][1] + red[0][2] + red[0][3];
  sq  = red[1][0] + red[1][1] + red[1][2] + red[1][3];
  float mu = sum * (1.f / CC);
  float var = sq * (1.f / CC) - mu * mu;
  float rs = rsqrtf(var + 1e-5f);
  float* orow = out + (size_t)row * CC;
  int t = row % TT;
  float* lrow = (t == TT - 1) ? (last_out + (size_t)(row / TT) * CC) : nullptr;
#pragma unroll
  for (int i = 0; i < 8; ++i) {
    int c = threadIdx.x + 256 * i;
    float y = (vals[i] - mu) * rs * w[c] + b[c];
    orow[c] = y;
    if (lrow) lrow[c] = y;
  }
}

// ------------------------------------------------- fused x2 = x+p0+p1 ; LN2(x2)
__global__ __launch_bounds__(256) void add_ln_kernel(
    const float* __restrict__ p0, const float* __restrict__ p1,
    const float* __restrict__ x, const float* __restrict__ w,
    const float* __restrict__ b, float* __restrict__ x2out,
    float* __restrict__ xnout, float* __restrict__ last_out) {
  int row = blockIdx.x;
  const size_t rb = (size_t)row * CC;
  float vals[8];
  float sum = 0.f, sq = 0.f;
#pragma unroll
  for (int i = 0; i < 8; ++i) {
    int c = threadIdx.x + 256 * i;
    float v = x[rb + c] + p0[rb + c] + p1[rb + c];
    vals[i] = v; sum += v; sq += v * v;
  }
#pragma unroll
  for (int off = 32; off; off >>= 1) {
    sum += __shfl_xor(sum, off);
    sq  += __shfl_xor(sq, off);
  }
  __shared__ float red[2][4];
  int lane = threadIdx.x & 63, wv = threadIdx.x >> 6;
  if (lane == 0) { red[0][wv] = sum; red[1][wv] = sq; }
  __syncthreads();
  sum = red[0][0] + red[0][1] + red[0][2] + red[0][3];
  sq  = red[1][0] + red[1][1] + red[1][2] + red[1][3];
  float mu = sum * (1.f / CC);
  float var = sq * (1.f / CC) - mu * mu;
  float rs = rsqrtf(var + 1e-5f);
  int t = row % TT;
  float* lrow = (t == TT - 1) ? (last_out + (size_t)(row / TT) * CC) : nullptr;
#pragma unroll
  for (int i = 0; i < 8; ++i) {
    int c = threadIdx.x + 256 * i;
    float v = vals[i];
    x2out[rb + c] = v;
    float y = (v - mu) * rs * w[c] + b[c];
    xnout[rb + c] = y;
    if (lrow) lrow[c] = y;
  }
}

// ------------------------------------------------- token-shift mix input
__global__ __launch_bounds__(256) void mixin_kernel(
    const float* __restrict__ xn, const float* __restrict__ tms,
    const float* __restrict__ maa_x, float* __restrict__ out) {
  int idx = blockIdx.x * 256 + threadIdx.x;
  int c = idx & (CC - 1);
  int row = idx >> 11;
  int t = row & (TT - 1);
  int b = row >> 10;
  float xv = xn[idx];
  float pv = (t == 0) ? tms[b * CC + c] : xn[idx - CC];
  out[idx] = xv + (pv - xv) * maa_x[c];
}

// ------------------------------------------------- channel-mix shift (bf16 out)
__global__ __launch_bounds__(256) void mix2_kernel(
    const float* __restrict__ xn2, const float* __restrict__ cms,
    const float* __restrict__ fk, const float* __restrict__ fr,
    ushort_t* __restrict__ xk2, ushort_t* __restrict__ xr2) {
  int idx = blockIdx.x * 256 + threadIdx.x;
  int c = idx & (CC - 1);
  int row = idx >> 11;
  int t = row & (TT - 1);
  int b = row >> 10;
  float xv = xn2[idx];
  float pv = (t == 0) ? cms[b * CC + c] : xn2[idx - CC];
  float kf = fk[c], rf = fr[c];
  xk2[idx] = f2bf(pv * kf + xv * (1.f - kf));
  xr2[idx] = f2bf(pv * rf + xv * (1.f - rf));
}

// ------------------------------------------------- split-K skinny fp32 GEMM
__global__ __launch_bounds__(256) void gemm_splitk(
    const float* __restrict__ A, int lda,
    const float* __restrict__ W, int N,
    float* __restrict__ parts, int ntiles, int kslice, int M) {
  __shared__ float As[16][68];
  __shared__ float Ws[16][68];
  const int tid = threadIdx.x;
  const int m0 = blockIdx.x * 64;
  const int n0 = blockIdx.y * 64;
  const int s = blockIdx.z;
  const int kb = s * kslice;
  const int tx = tid & 15, ty = tid >> 4;
  float acc[4][4];
#pragma unroll
  for (int i = 0; i < 4; ++i)
#pragma unroll
    for (int j = 0; j < 4; ++j) acc[i][j] = 0.f;
  for (int k0 = 0; k0 < kslice; k0 += 16) {
    {
      int r = tid >> 2, c = (tid & 3) * 4;
      float4 v = *(const float4*)(A + (size_t)(m0 + r) * lda + kb + k0 + c);
      As[c + 0][r] = v.x; As[c + 1][r] = v.y; As[c + 2][r] = v.z; As[c + 3][r] = v.w;
    }
#pragma unroll
    for (int i = 0; i < 4; ++i) {
      int idx = tid + 256 * i;
      int kr = idx >> 6, nc = idx & 63;
      int n = n0 + nc;
      Ws[kr][nc] = (n < N) ? W[(size_t)(kb + k0 + kr) * N + n] : 0.f;
    }
    __syncthreads();
#pragma unroll
    for (int k = 0; k < 16; ++k) {
      float a[4], w4[4];
#pragma unroll
      for (int i = 0; i < 4; ++i) a[i] = As[k][ty * 4 + i];
#pragma unroll
      for (int j = 0; j < 4; ++j) w4[j] = Ws[k][tx * 4 + j];
#pragma unroll
      for (int i = 0; i < 4; ++i)
#pragma unroll
        for (int j = 0; j < 4; ++j) acc[i][j] = fmaf(a[i], w4[j], acc[i][j]);
    }
    __syncthreads();
  }
  const int NP = ntiles * 64;
  float* pb = parts + (size_t)s * M * NP;
#pragma unroll
  for (int i = 0; i < 4; ++i) {
    int m = m0 + ty * 4 + i;
    float4 v = {acc[i][0], acc[i][1], acc[i][2], acc[i][3]};
    *(float4*)(pb + (size_t)m * NP + n0 + tx * 4) = v;
  }
}

__global__ __launch_bounds__(256) void combine_tanh(
    const float* __restrict__ parts, int NP, int M, int Nreal, int S,
    float* __restrict__ out) {
  int idx = blockIdx.x * 256 + threadIdx.x;
  if (idx >= M * Nreal) return;
  int m = idx / Nreal, n = idx - m * Nreal;
  float acc = 0.f;
  for (int s = 0; s < S; ++s) acc += parts[(size_t)s * M * NP + (size_t)m * NP + n];
  out[idx] = tanhf(acc);
}

// ------------------------------------------------- fp32 tiled GEMM (decay -exp only)
__global__ __launch_bounds__(256) void gemm_negexp(
    const float* __restrict__ A, int lda,
    const float* __restrict__ B, int ldb,
    float* __restrict__ out, int N, int K,
    const float* __restrict__ td) {
  __shared__ float As[16][132];
  __shared__ float Bs[16][132];
  const int tid = threadIdx.x;
  const int tx = tid & 15, ty = tid >> 4;
  const int m0 = blockIdx.y * 128, n0 = blockIdx.x * 128;
  float acc[8][8];
#pragma unroll
  for (int i = 0; i < 8; ++i)
#pragma unroll
    for (int j = 0; j < 8; ++j) acc[i][j] = 0.f;
  for (int k0 = 0; k0 < K; k0 += 16) {
    {
      int r = tid >> 1, c = (tid & 1) * 8;
      const float* src = A + (size_t)(m0 + r) * lda + k0 + c;
      float4 v0 = *(const float4*)src;
      float4 v1 = *(const float4*)(src + 4);
      As[c + 0][r] = v0.x; As[c + 1][r] = v0.y; As[c + 2][r] = v0.z; As[c + 3][r] = v0.w;
      As[c + 4][r] = v1.x; As[c + 5][r] = v1.y; As[c + 6][r] = v1.z; As[c + 7][r] = v1.w;
    }
#pragma unroll
    for (int i = 0; i < 2; ++i) {
      int idx = tid + 256 * i;
      int kk = idx >> 5, nn = (idx & 31) * 4;
      float4 v = *(const float4*)(B + (size_t)(k0 + kk) * ldb + n0 + nn);
      *(float4*)&Bs[kk][nn] = v;
    }
    __syncthreads();
#pragma unroll
    for (int k = 0; k < 16; ++k) {
      float a[8], bb[8];
      *(float4*)&a[0] = *(const float4*)&As[k][ty * 8];
      *(float4*)&a[4] = *(const float4*)&As[k][ty * 8 + 4];
      *(float4*)&bb[0] = *(const float4*)&Bs[k][tx * 8];
      *(float4*)&bb[4] = *(const float4*)&Bs[k][tx * 8 + 4];
#pragma unroll
      for (int i = 0; i < 8; ++i)
#pragma unroll
        for (int j = 0; j < 8; ++j) acc[i][j] = fmaf(a[i], bb[j], acc[i][j]);
    }
    __syncthreads();
  }
#pragma unroll
  for (int i = 0; i < 8; ++i) {
    int row = m0 + ty * 8 + i;
#pragma unroll
    for (int j = 0; j < 8; ++j) {
      int col = n0 + tx * 8 + j;
      out[(size_t)row * N + col] = -expf(td[col] + acc[i][j]);
    }
  }
}

// ------------------------------------------------- mix5: broadcast row-block kernel
struct Mix5Args {
  const float* maa[5];
  float* xw;
  ushort_t* ob[4];   // xk, xv, xr, xg
};

__global__ __launch_bounds__(256) void mix5_gemm(
    const float* __restrict__ hh, const float* __restrict__ w2,
    const float* __restrict__ xn, const float* __restrict__ tms, Mix5Args args) {
  const int f = blockIdx.y;
  const int rb = blockIdx.x;           // 8 rows per block
  const int tid = threadIdx.x;
  __shared__ float hh8[8][32];
  {
    int r = tid >> 5, k = tid & 31;
    hh8[r][k] = hh[(size_t)(rb * 8 + r) * 160 + f * 32 + k];
  }
  __syncthreads();
  const float* maa = args.maa[f];
  const float* w2f = w2 + (size_t)f * 32 * CC;
#pragma unroll
  for (int chunk = 0; chunk < 2; ++chunk) {
    const int col = chunk * 1024 + tid * 4;
    float4 w2v[32];
#pragma unroll
    for (int k = 0; k < 32; ++k)
      w2v[k] = *(const float4*)(w2f + (size_t)k * CC + col);
    const float4 maa4 = *(const float4*)(maa + col);
#pragma unroll
    for (int r = 0; r < 8; ++r) {
      const int row = rb * 8 + r;
      float4 acc = {0.f, 0.f, 0.f, 0.f};
#pragma unroll
      for (int k4 = 0; k4 < 8; ++k4) {
        float4 h = *(const float4*)&hh8[r][k4 * 4];
        FMA4(acc, h.x, w2v[k4 * 4 + 0]);
        FMA4(acc, h.y, w2v[k4 * 4 + 1]);
        FMA4(acc, h.z, w2v[k4 * 4 + 2]);
        FMA4(acc, h.w, w2v[k4 * 4 + 3]);
      }
      const int t = row & (TT - 1);
      const size_t oi = (size_t)row * CC + col;
      float4 xv = *(const float4*)(xn + oi);
      float4 pv;
      if (t == 0) pv = *(const float4*)(tms + (size_t)(row >> 10) * CC + col);
      else        pv = *(const float4*)(xn + oi - CC);
      float4 v;
      v.x = xv.x + (pv.x - xv.x) * (maa4.x + acc.x);
      v.y = xv.y + (pv.y - xv.y) * (maa4.y + acc.y);
      v.z = xv.z + (pv.z - xv.z) * (maa4.z + acc.z);
      v.w = xv.w + (pv.w - xv.w) * (maa4.w + acc.w);
      if (f == 0) {
        *(float4*)(args.xw + oi) = v;
      } else {
        ushort4 o;
        o.x = f2bf(v.x); o.y = f2bf(v.y); o.z = f2bf(v.z); o.w = f2bf(v.w);
        *(ushort4*)(args.ob[f - 1] + oi) = o;
      }
    }
  }
}

// ================================================= g9: 256x128 pipelined MFMA GEMM
template <bool IS_A>
__device__ __forceinline__ void g9_stage(
    char* buf, const ushort_t* g, int ld, int r0, int k0, int tid) {
  constexpr int NJ = IS_A ? 4 : 2;
  char* dst = buf + (IS_A ? 0 : 32768);
#pragma unroll
  for (int j = 0; j < NJ; ++j) {
    int L = j * 8192 + tid * 16;
    int P = L ^ (((L >> 7) & 7) << 4);
    int r = P >> 7, cb = (P & 127) >> 1;
    gload16(g + (size_t)(r0 + r) * ld + k0 + cb, (ushort_t*)(dst + L));
  }
}

__device__ __forceinline__ void g9_core(
    const ushort_t* gA, int lda, const ushort_t* gB, int ldb,
    int m0, int n0, int kstart, int K, char* lds, f32x4 (*acc)[4]) {
  const int tid = threadIdx.x, w = tid >> 6, l = tid & 63;
  const int wr = w >> 1, wc = w & 1;
  const int r16 = l & 15, h16 = (l >> 4) * 16;
  const int NT = K >> 6;
  g9_stage<true>(lds, gA, lda, m0, kstart, tid);
  g9_stage<false>(lds, gB, ldb, n0, kstart, tid);
  g9_stage<true>(lds + 49152, gA, lda, m0, kstart + 64, tid);
  g9_stage<false>(lds + 49152, gB, ldb, n0, kstart + 64, tid);
  int cur = 0;
  for (int t = 0; t < NT; ++t) {
    char* bufc = lds + cur * 49152;
    int nxt = cur + 2; if (nxt >= 3) nxt -= 3;
    char* bufn = lds + nxt * 49152;
    if (t + 1 < NT) asm volatile("s_waitcnt vmcnt(6)" ::: "memory");
    else            asm volatile("s_waitcnt vmcnt(0)" ::: "memory");
    __builtin_amdgcn_s_barrier();
    const bool pf = (t + 2 < NT);
    const int k2 = kstart + (t + 2) * 64;
    // ---- phase kh=0
    {
      bf16x8 a[4], b[4];
#pragma unroll
      for (int mf = 0; mf < 4; ++mf) {
        int row = wr * 64 + mf * 16 + r16;
        int off = h16 ^ ((row & 7) << 4);
        a[mf] = *(const bf16x8*)(bufc + row * 128 + off);
      }
#pragma unroll
      for (int nf = 0; nf < 4; ++nf) {
        int row = wc * 64 + nf * 16 + r16;
        int off = h16 ^ ((row & 7) << 4);
        b[nf] = *(const bf16x8*)(bufc + 32768 + row * 128 + off);
      }
      if (pf) g9_stage<true>(bufn, gA, lda, m0, k2, tid);
      __builtin_amdgcn_s_setprio(1);
#pragma unroll
      for (int mf = 0; mf < 4; ++mf)
#pragma unroll
        for (int nf = 0; nf < 4; ++nf)
          acc[mf][nf] = __builtin_amdgcn_mfma_f32_16x16x32_bf16(a[mf], b[nf], acc[mf][nf], 0, 0, 0);
      __builtin_amdgcn_s_setprio(0);
    }
    // ---- phase kh=1
    {
      bf16x8 a[4], b[4];
#pragma unroll
      for (int mf = 0; mf < 4; ++mf) {
        int row = wr * 64 + mf * 16 + r16;
        int off = (64 + h16) ^ ((row & 7) << 4);
        a[mf] = *(const bf16x8*)(bufc + row * 128 + off);
      }
#pragma unroll
      for (int nf = 0; nf < 4; ++nf) {
        int row = wc * 64 + nf * 16 + r16;
        int off = (64 + h16) ^ ((row & 7) << 4);
        b[nf] = *(const bf16x8*)(bufc + 32768 + row * 128 + off);
      }
      if (pf) g9_stage<false>(bufn, gB, ldb, n0, k2, tid);
      __builtin_amdgcn_s_setprio(1);
#pragma unroll
      for (int mf = 0; mf < 4; ++mf)
#pragma unroll
        for (int nf = 0; nf < 4; ++nf)
          acc[mf][nf] = __builtin_amdgcn_mfma_f32_16x16x32_bf16(a[mf], b[nf], acc[mf][nf], 0, 0, 0);
      __builtin_amdgcn_s_setprio(0);
    }
    cur += 1; if (cur == 3) cur = 0;
  }
}

#define G9_INIT_ACC f32x4 acc[4][4]; \
  _Pragma("unroll") for (int i0 = 0; i0 < 4; ++i0) \
  _Pragma("unroll") for (int i1 = 0; i1 < 4; ++i1) acc[i0][i1] = {0.f, 0.f, 0.f, 0.f};

// r,k,v,g batched: blockIdx.z selects which GEMM; outputs bf16
struct RkvgArgs {
  const ushort_t* A[4];
  const ushort_t* W[4];
  ushort_t* O[4];
};

__global__ __launch_bounds__(512, 2) void g9_rkvg(RkvgArgs args) {
  __shared__ __align__(16) char lds[147456];
  const int z = blockIdx.z;
  const int m0 = blockIdx.y * 256, n0 = blockIdx.x * 128;
  G9_INIT_ACC
  g9_core(args.A[z], CC, args.W[z], CC, m0, n0, 0, CC, lds, acc);
  const int tid = threadIdx.x, w = tid >> 6, l = tid & 63;
  const int wr = w >> 1, wc = w & 1, r16 = l & 15, q4 = (l >> 4) * 4;
  ushort_t* out = args.O[z];
  const bool silu = (z == 3);
#pragma unroll
  for (int mf = 0; mf < 4; ++mf)
#pragma unroll
    for (int nf = 0; nf < 4; ++nf) {
      int col = n0 + wc * 64 + nf * 16 + r16;
#pragma unroll
      for (int j = 0; j < 4; ++j) {
        int row = m0 + wr * 64 + mf * 16 + q4 + j;
        float v = acc[mf][nf][j];
        if (silu) v = v / (1.f + expf(-v));
        out[(size_t)row * CC + col] = f2bf(v);
      }
    }
}

__global__ __launch_bounds__(512, 2) void g9_relu2(
    const ushort_t* __restrict__ A, int lda,
    const ushort_t* __restrict__ W, int ldb,
    ushort_t* __restrict__ out, int N, int K) {
  __shared__ __align__(16) char lds[147456];
  const int m0 = blockIdx.y * 256, n0 = blockIdx.x * 128;
  G9_INIT_ACC
  g9_core(A, lda, W, ldb, m0, n0, 0, K, lds, acc);
  const int tid = threadIdx.x, w = tid >> 6, l = tid & 63;
  const int wr = w >> 1, wc = w & 1, r16 = l & 15, q4 = (l >> 4) * 4;
#pragma unroll
  for (int mf = 0; mf < 4; ++mf)
#pragma unroll
    for (int nf = 0; nf < 4; ++nf) {
      int col = n0 + wc * 64 + nf * 16 + r16;
#pragma unroll
      for (int j = 0; j < 4; ++j) {
        int row = m0 + wr * 64 + mf * 16 + q4 + j;
        float r_ = fmaxf(acc[mf][nf][j], 0.f);
        out[(size_t)row * N + col] = f2bf(r_ * r_);
      }
    }
}

struct SkArgs {
  const ushort_t* A;
  const ushort_t* W;
  float* P[2];
  int lda, ldb, klen;
};

__global__ __launch_bounds__(512, 2) void g9_sk(SkArgs args) {
  __shared__ __align__(16) char lds[147456];
  const int z = blockIdx.z;
  const int m0 = blockIdx.y * 256, n0 = blockIdx.x * 128;
  G9_INIT_ACC
  g9_core(args.A, args.lda, args.W, args.ldb, m0, n0, z * args.klen, args.klen, lds, acc);
  const int tid = threadIdx.x, w = tid >> 6, l = tid & 63;
  const int wr = w >> 1, wc = w & 1, r16 = l & 15, q4 = (l >> 4) * 4;
  float* out = args.P[z];
#pragma unroll
  for (int mf = 0; mf < 4; ++mf)
#pragma unroll
    for (int nf = 0; nf < 4; ++nf) {
      int col = n0 + wc * 64 + nf * 16 + r16;
#pragma unroll
      for (int j = 0; j < 4; ++j) {
        int row = m0 + wr * 64 + mf * 16 + q4 + j;
        out[(size_t)row * CC + col] = acc[mf][nf][j];
      }
    }
}

// ------------------------------------------------- split-K combines (vectorized)
__global__ __launch_bounds__(256) void comb_sig2(
    const float* __restrict__ p0, const float* __restrict__ p1,
    float* __restrict__ out, int n4) {
  int i = blockIdx.x * 256 + threadIdx.x;
  int stride = gridDim.x * 256;
  for (; i < n4; i += stride) {
    float4 a = ((const float4*)p0)[i];
    float4 b = ((const float4*)p1)[i];
    float4 o;
    o.x = 1.f / (1.f + expf(-(a.x + b.x)));
    o.y = 1.f / (1.f + expf(-(a.y + b.y)));
    o.z = 1.f / (1.f + expf(-(a.z + b.z)));
    o.w = 1.f / (1.f + expf(-(a.w + b.w)));
    ((float4*)out)[i] = o;
  }
}

__global__ __launch_bounds__(256) void comb_fma2(
    const float* __restrict__ p0, const float* __restrict__ p1,
    const float* __restrict__ x2, const float* __restrict__ sig,
    float* __restrict__ out, int n4) {
  int i = blockIdx.x * 256 + threadIdx.x;
  int stride = gridDim.x * 256;
  for (; i < n4; i += stride) {
    float4 a = ((const float4*)p0)[i];
    float4 b = ((const float4*)p1)[i];
    float4 xx = ((const float4*)x2)[i];
    float4 ss = ((const float4*)sig)[i];
    float4 o;
    o.x = fmaf(ss.x, a.x + b.x, xx.x);
    o.y = fmaf(ss.y, a.y + b.y, xx.y);
    o.z = fmaf(ss.z, a.z + b.z, xx.z);
    o.w = fmaf(ss.w, a.w + b.w, xx.w);
    ((float4*)out)[i] = o;
  }
}

// ================================================= chunked WKV scan (bf16 r,k,v)
__global__ __launch_bounds__(256) void wkv_chunk1(
    const ushort_t* __restrict__ r, const ushort_t* __restrict__ k,
    const ushort_t* __restrict__ v, const float* __restrict__ w,
    const float* __restrict__ u,
    float* __restrict__ rtG, float* __restrict__ Pg,
    float* __restrict__ dg, float* __restrict__ o_intra) {
  __shared__ __align__(16) float lds[4 * 4160];
  float* Ech = lds;                 // [64][64] inclusive cumsum C
  float* Ach = lds;                 // [64][65] A, aliases Ech after stage 2
  float* rtl = lds + 4160;          // [64][65]
  float* ktl = lds + 2 * 4160;      // [64][65]
  float* Vl  = lds + 3 * 4160;      // [64][65]
  __shared__ float Dl[64], dl[64];
  const int c = blockIdx.x, bh = blockIdx.y;
  const int b = bh >> 5, h = bh & 31;
  const int tid = threadIdx.x;
  const size_t base = (size_t)b * TT * CC + (size_t)(c * LCH) * CC + h * KK;
  for (int i = 0; i < 16; ++i) {
    int e = tid + 256 * i;
    int row = e >> 6, col = e & 63;
    size_t g = base + (size_t)row * CC + col;
    rtl[row * 65 + col] = b2f(r[g]);
    ktl[row * 65 + col] = b2f(k[g]);
    Vl[row * 65 + col] = b2f(v[g]);
  }
  if (tid < 64) {
    float cum = 0.f;
#pragma unroll 8
    for (int i = 0; i < 64; ++i) {
      cum += w[base + (size_t)i * CC + tid];
      Ech[i * 64 + tid] = cum;
    }
    float dd = expf(cum);
    dl[tid] = dd;
    dg[(size_t)(bh * NCH + c) * 64 + tid] = dd;
  }
  __syncthreads();
  {
    const int g = tid >> 6, kk = tid & 63;
    const float uk = u[h * KK + kk];
    for (int i = 0; i < 16; ++i) {
      int t = i * 4 + g;
      float Cv = Ech[t * 64 + kk];
      float Ev = (t == 0) ? 0.f : Ech[(t - 1) * 64 + kk];
      float rraw = rtl[t * 65 + kk];
      float kraw = ktl[t * 65 + kk];
      float rtv = rraw * expf(Ev);
      float ktv = kraw * expf(-Cv);
      rtl[t * 65 + kk] = rtv;
      ktl[t * 65 + kk] = ktv;
      rtG[((size_t)(bh * NCH + c) * 64 + t) * 64 + kk] = rtv;
      float prod = rraw * uk * kraw;
#pragma unroll
      for (int off = 32; off; off >>= 1) prod += __shfl_xor(prod, off);
      if (kk == 0) Dl[t] = prod;
    }
  }
  __syncthreads();
  {
    const int ti = tid >> 4, tj = tid & 15;
    float a4[4][4];
#pragma unroll
    for (int a = 0; a < 4; ++a)
#pragma unroll
      for (int q = 0; q < 4; ++q) a4[a][q] = 0.f;
    for (int kk = 0; kk < 64; ++kk) {
      float ra[4], kb[4];
#pragma unroll
      for (int a = 0; a < 4; ++a) ra[a] = rtl[(4 * ti + a) * 65 + kk];
#pragma unroll
      for (int q = 0; q < 4; ++q) kb[q] = ktl[(4 * tj + q) * 65 + kk];
#pragma unroll
      for (int a = 0; a < 4; ++a)
#pragma unroll
        for (int q = 0; q < 4; ++q) a4[a][q] = fmaf(ra[a], kb[q], a4[a][q]);
    }
#pragma unroll
    for (int a = 0; a < 4; ++a) {
      int i = 4 * ti + a;
#pragma unroll
      for (int q = 0; q < 4; ++q) {
        int j = 4 * tj + q;
        Ach[i * 65 + j] = (j < i) ? a4[a][q] : (j == i ? Dl[i] : 0.f);
      }
    }
  }
  __syncthreads();
  {
    const int tr = tid >> 4, tv = tid & 15;
    float o4[4][4], p4[4][4];
#pragma unroll
    for (int a = 0; a < 4; ++a)
#pragma unroll
      for (int q = 0; q < 4; ++q) { o4[a][q] = 0.f; p4[a][q] = 0.f; }
    for (int j = 0; j < 64; ++j) {
      float av[4], kv4[4], vv[4];
#pragma unroll
      for (int a = 0; a < 4; ++a) av[a] = Ach[(4 * tr + a) * 65 + j];
#pragma unroll
      for (int a = 0; a < 4; ++a) kv4[a] = ktl[j * 65 + 4 * tr + a];
#pragma unroll
      for (int q = 0; q < 4; ++q) vv[q] = Vl[j * 65 + 4 * tv + q];
#pragma unroll
      for (int a = 0; a < 4; ++a)
#pragma unroll
        for (int q = 0; q < 4; ++q) {
          o4[a][q] = fmaf(av[a], vv[q], o4[a][q]);
          p4[a][q] = fmaf(kv4[a], vv[q], p4[a][q]);
        }
    }
#pragma unroll
    for (int a = 0; a < 4; ++a) {
      int i = 4 * tr + a;
      float4 ov = {o4[a][0], o4[a][1], o4[a][2], o4[a][3]};
      *(float4*)(o_intra + base + (size_t)i * CC + 4 * tv) = ov;
    }
#pragma unroll
    for (int a = 0; a < 4; ++a) {
      int kk2 = 4 * tr + a;
      float dd = dl[kk2];
      float4 pv = {p4[a][0] * dd, p4[a][1] * dd, p4[a][2] * dd, p4[a][3] * dd};
      *(float4*)(Pg + ((size_t)(bh * NCH + c) * 64 + kk2) * 64 + 4 * tv) = pv;
    }
  }
}

__global__ __launch_bounds__(256) void wkv_chain(
    const float* __restrict__ P, const float* __restrict__ d,
    const float* __restrict__ s0, float* __restrict__ s_starts,
    float* __restrict__ s_out) {
  const int bh = blockIdx.x;
  const int tid = threadIdx.x;
  float s[16];
#pragma unroll
  for (int m = 0; m < 16; ++m) s[m] = s0[(size_t)bh * 4096 + tid + 256 * m];
  for (int c = 0; c < NCH; ++c) {
    size_t cb = (size_t)(bh * NCH + c) * 4096;
#pragma unroll
    for (int m = 0; m < 16; ++m) {
      int idx = tid + 256 * m;
      s_starts[cb + idx] = s[m];
      float dd = d[(size_t)(bh * NCH + c) * 64 + (idx >> 6)];
      s[m] = fmaf(dd, s[m], P[cb + idx]);
    }
  }
#pragma unroll
  for (int m = 0; m < 16; ++m) s_out[(size_t)bh * 4096 + tid + 256 * m] = s[m];
}

__global__ __launch_bounds__(256) void wkv_chunk2(
    const float* __restrict__ rtG, const float* __restrict__ s_starts,
    const float* __restrict__ o_intra, const ushort_t* __restrict__ g,
    const float* __restrict__ lnw, const float* __restrict__ lnb,
    ushort_t* __restrict__ ym) {
  __shared__ __align__(16) float lds[3 * 4160];
  float* rtl = lds;             // [64][65] t x k
  float* sl  = lds + 4160;      // [64][65] k x v
  float* ol  = lds + 2 * 4160;  // [64][65] t x v
  __shared__ float mul[64], rsl[64];
  const int c = blockIdx.x, bh = blockIdx.y;
  const int b = bh >> 5, h = bh & 31;
  const int tid = threadIdx.x;
  const size_t base = (size_t)b * TT * CC + (size_t)(c * LCH) * CC + h * KK;
  const size_t cb = (size_t)(bh * NCH + c) * 4096;
  for (int i = 0; i < 16; ++i) {
    int e = tid + 256 * i;
    int row = e >> 6, col = e & 63;
    rtl[row * 65 + col] = rtG[cb + e];
    sl[row * 65 + col] = s_starts[cb + e];
  }
  __syncthreads();
  {
    const int tr = tid >> 4, tv = tid & 15;
    float o4[4][4];
#pragma unroll
    for (int a = 0; a < 4; ++a)
#pragma unroll
      for (int q = 0; q < 4; ++q) o4[a][q] = 0.f;
    for (int kk = 0; kk < 64; ++kk) {
      float ra[4], sv[4];
#pragma unroll
      for (int a = 0; a < 4; ++a) ra[a] = rtl[(4 * tr + a) * 65 + kk];
#pragma unroll
      for (int q = 0; q < 4; ++q) sv[q] = sl[kk * 65 + 4 * tv + q];
#pragma unroll
      for (int a = 0; a < 4; ++a)
#pragma unroll
        for (int q = 0; q < 4; ++q) o4[a][q] = fmaf(ra[a], sv[q], o4[a][q]);
    }
#pragma unroll
    for (int a = 0; a < 4; ++a) {
      int i = 4 * tr + a;
      float4 oi = *(const float4*)(o_intra + base + (size_t)i * CC + 4 * tv);
      ol[i * 65 + 4 * tv + 0] = o4[a][0] + oi.x;
      ol[i * 65 + 4 * tv + 1] = o4[a][1] + oi.y;
      ol[i * 65 + 4 * tv + 2] = o4[a][2] + oi.z;
      ol[i * 65 + 4 * tv + 3] = o4[a][3] + oi.w;
    }
  }
  __syncthreads();
  {
    int row = tid >> 2, q = tid & 3;
    float sum = 0.f, sq = 0.f;
#pragma unroll
    for (int j = 0; j < 16; ++j) {
      float val = ol[row * 65 + q * 16 + j];
      sum += val; sq += val * val;
    }
    sum += __shfl_xor(sum, 1); sq += __shfl_xor(sq, 1);
    sum += __shfl_xor(sum, 2); sq += __shfl_xor(sq, 2);
    if (q == 0) {
      float mu = sum * (1.f / 64.f);
      float var = sq * (1.f / 64.f) - mu * mu;
      mul[row] = mu;
      rsl[row] = rsqrtf(var + 6.4e-4f);
    }
  }
  __syncthreads();
  for (int i = 0; i < 16; ++i) {
    int e = tid + 256 * i;
    int row = e >> 6, col = e & 63;
    float val = (ol[row * 65 + col] - mul[row]) * rsl[row];
    val = val * lnw[h * KK + col] + lnb[h * KK + col];
    size_t gi = base + (size_t)row * CC + col;
    ym[gi] = f2bf(val * b2f(g[gi]));
  }
}

// =================================================================== launch
extern "C" void kernel_launch(void* const* d_in, const int* in_sizes, int n_in,
                              void* d_out, int out_size, void* d_ws, size_t ws_size,
                              hipStream_t stream) {
  const float* x    = (const float*)d_in[0];
  const float* tms  = (const float*)d_in[1];
  const float* cms  = (const float*)d_in[2];
  const float* tmstate = (const float*)d_in[3];
  const float* ln1_w = (const float*)d_in[4];
  const float* ln1_b = (const float*)d_in[5];
  const float* ln2_w = (const float*)d_in[6];
  const float* ln2_b = (const float*)d_in[7];
  const float* maa_x = (const float*)d_in[8];
  const float* maa_w = (const float*)d_in[9];
  const float* maa_k = (const float*)d_in[10];
  const float* maa_v = (const float*)d_in[11];
  const float* maa_r = (const float*)d_in[12];
  const float* maa_g = (const float*)d_in[13];
  const float* maa_w1 = (const float*)d_in[14];
  const float* maa_w2 = (const float*)d_in[15];
  const float* td    = (const float*)d_in[16];
  const float* td_w1 = (const float*)d_in[17];
  const float* td_w2 = (const float*)d_in[18];
  const float* u     = (const float*)d_in[19];
  const float* Wr    = (const float*)d_in[20];
  const float* Wk    = (const float*)d_in[21];
  const float* Wv    = (const float*)d_in[22];
  const float* Wg    = (const float*)d_in[23];
  const float* Wo    = (const float*)d_in[24];
  const float* lnx_w = (const float*)d_in[25];
  const float* lnx_b = (const float*)d_in[26];
  const float* fmk   = (const float*)d_in[27];
  const float* fmr   = (const float*)d_in[28];
  const float* fWk   = (const float*)d_in[29];
  const float* fWr   = (const float*)d_in[30];
  const float* fWv   = (const float*)d_in[31];
  (void)in_sizes; (void)n_in; (void)out_size;

  const size_t SLOT = (size_t)BTROWS * CC;   // 4M elements
  float* F[7];
  for (int i = 0; i < 7; ++i) F[i] = (float*)d_ws + i * SLOT;
  ushort_t* B0 = (ushort_t*)((float*)d_ws + 7 * SLOT);
  ushort_t* B1 = B0 + SLOT;
  ushort_t* B2 = B1 + SLOT;
  ushort_t* B3 = B2 + SLOT;
  ushort_t* WBIG = B3 + SLOT;                    // 4*CC*CC; later fWkB
  ushort_t* WrB = WBIG;
  ushort_t* WkB = WrB + (size_t)CC * CC;
  ushort_t* WvB = WkB + (size_t)CC * CC;
  ushort_t* WgB = WvB + (size_t)CC * CC;
  ushort_t* WoB = WBIG + (size_t)4 * CC * CC;    // CC*CC; later fWrB
  ushort_t* fWvB = WoB + (size_t)CC * CC;        // CC*FFD
  float* hh  = (float*)(fWvB + (size_t)CC * FFD);
  float* tmpd = hh + (size_t)BTROWS * 160;
  size_t need = (size_t)((char*)(tmpd + (size_t)BTROWS * 64) - (char*)d_ws);
  if (ws_size < need) return;
  ushort_t* fWkB = WBIG;
  ushort_t* fWrB = WoB;
  ushort_t* h1   = (ushort_t*)F[5];              // spans F5+F6

  // bf16 r,k,v,g live in F3..F6 (reinterpreted; g persists through chunk2,
  // h1 overwrites F5/F6 only afterwards)
  ushort_t* rB = (ushort_t*)F[3];
  ushort_t* kB = (ushort_t*)F[4];
  ushort_t* vB = (ushort_t*)F[5];
  ushort_t* gB = (ushort_t*)F[6];

  // scan scratch (reuses dead regions)
  float* rtG = F[1];
  float* o_intra = F[0];
  float* s_starts = (float*)B0;      // spans B0,B1
  float* Pg = (float*)B2;            // spans B2,B3
  float* dbuf = (float*)(WBIG + (size_t)FFD * CC);
  ushort_t* ym = B3;

  // split-K parts
  float* partsW1 = F[4];
  float* partsTD = F[5];

  float* out_x    = (float*)d_out;
  float* out_shift = out_x + (size_t)BB * TT * CC;
  float* out_cm   = out_shift + (size_t)BB * CC;
  float* out_wkv  = out_cm + (size_t)BB * CC;

  const dim3 blk256(256);
  const dim3 blk512(512);

  // 0. weight conversions (5 CC^2 batched + fWv)
  {
    Cvt5Args ca;
    ca.in[0] = Wr; ca.in[1] = Wk; ca.in[2] = Wv; ca.in[3] = Wg; ca.in[4] = Wo;
    ca.out[0] = WrB; ca.out[1] = WkB; ca.out[2] = WvB; ca.out[3] = WgB; ca.out[4] = WoB;
    cvt5_kernel<<<dim3(512, 5), blk256, 0, stream>>>(ca);
  }
  cvt_kernel<<<2048, blk256, 0, stream>>>(fWv, fWvB, CC * FFD / 4);

  // 1. xn = LN(x) -> F0, new_shift
  ln_kernel<<<BTROWS, blk256, 0, stream>>>(x, ln1_w, ln1_b, F[0], out_shift);
  // 2. mixin -> F3
  mixin_kernel<<<(BTROWS * CC) / 256, blk256, 0, stream>>>(F[0], tms, maa_x, F[3]);
  // 3. hh = tanh(mixin @ maa_w1)  (split-K)
  gemm_splitk<<<dim3(BTROWS / 64, 3, 8), blk256, 0, stream>>>(
      F[3], CC, maa_w1, 160, partsW1, 3, CC / 8, BTROWS);
  combine_tanh<<<(BTROWS * 160 + 255) / 256, blk256, 0, stream>>>(
      partsW1, 192, BTROWS, 160, 8, hh);
  // 4. mix5: xw->F1 (f32), xk->B1, xv->B2, xr->B3, xg->B0 (bf16)
  {
    Mix5Args ma;
    ma.maa[0] = maa_w; ma.maa[1] = maa_k; ma.maa[2] = maa_v; ma.maa[3] = maa_r; ma.maa[4] = maa_g;
    ma.xw = F[1];
    ma.ob[0] = B1; ma.ob[1] = B2; ma.ob[2] = B3; ma.ob[3] = B0;
    mix5_gemm<<<dim3(BTROWS / 8, 5), blk256, 0, stream>>>(hh, maa_w2, F[0], tms, ma);
  }
  // 5. decay: tmpd = tanh(xw @ td_w1) (split-K); w = -exp(td + tmpd @ td_w2) -> F2
  gemm_splitk<<<dim3(BTROWS / 64, 1, 8), blk256, 0, stream>>>(
      F[1], CC, td_w1, 64, partsTD, 1, CC / 8, BTROWS);
  combine_tanh<<<(BTROWS * 64 + 255) / 256, blk256, 0, stream>>>(
      partsTD, 64, BTROWS, 64, 8, tmpd);
  gemm_negexp<<<dim3(16, 16), blk256, 0, stream>>>(tmpd, 64, td_w2, CC, F[2], CC, 64, td);
  // 6. r,k,v,g (g9, z-batched, bf16 out): r->F3, k->F4, v->F5, g->F6(silu)
  {
    RkvgArgs ra;
    ra.A[0] = B3; ra.A[1] = B1; ra.A[2] = B2; ra.A[3] = B0;
    ra.W[0] = WrB; ra.W[1] = WkB; ra.W[2] = WvB; ra.W[3] = WgB;
    ra.O[0] = rB; ra.O[1] = kB; ra.O[2] = vB; ra.O[3] = gB;
    g9_rkvg<<<dim3(16, 8, 4), blk512, 0, stream>>>(ra);
  }
  // convert fWk into WBIG (Wr..Wg dead after rkvg)
  cvt_kernel<<<2048, blk256, 0, stream>>>(fWk, fWkB, FFD * CC / 4);
  // 7. chunked WKV scan (bf16 r,k,v; f32 w)
  wkv_chunk1<<<dim3(NCH, BB * HH), blk256, 0, stream>>>(
      rB, kB, vB, F[2], u, rtG, Pg, dbuf, o_intra);
  wkv_chain<<<BB * HH, blk256, 0, stream>>>(Pg, dbuf, tmstate, s_starts, out_wkv);
  wkv_chunk2<<<dim3(NCH, BB * HH), blk256, 0, stream>>>(
      rtG, s_starts, o_intra, gB, lnx_w, lnx_b, ym);
  // 9. x2 = x + ym @ Wo^T (split-K x2, partials F0,F1)
  {
    SkArgs sa;
    sa.A = ym; sa.W = WoB; sa.lda = CC; sa.ldb = CC; sa.klen = CC / 2;
    sa.P[0] = F[0]; sa.P[1] = F[1];
    g9_sk<<<dim3(16, 8, 2), blk512, 0, stream>>>(sa);
  }
  // 10. fused: x2 -> F2, xn2 = LN2(x2) -> F1 (in-place over p1, safe), new_cm
  add_ln_kernel<<<BTROWS, blk256, 0, stream>>>(
      F[0], F[1], x, ln2_w, ln2_b, F[2], F[1], out_cm);
  // convert fWr into WoB region (Wo dead)
  cvt_kernel<<<2048, blk256, 0, stream>>>(fWr, fWrB, CC * CC / 4);
  // 11. xk2 -> B1, xr2 -> B2 (bf16)
  mix2_kernel<<<(BTROWS * CC) / 256, blk256, 0, stream>>>(F[1], cms, fmk, fmr, B1, B2);
  // 12. h1 = relu(xk2 @ fWk^T)^2 -> bf16, N=FFD
  g9_relu2<<<dim3(FFD / 128, 8), blk512, 0, stream>>>(B1, CC, fWkB, CC, h1, FFD, CC);
  // 13. sig = sigmoid(xr2 @ fWr^T) -> F4  (split-K x2, partials F0,F1)
  {
    SkArgs ss;
    ss.A = B2; ss.W = fWrB; ss.lda = CC; ss.ldb = CC; ss.klen = CC / 2;
    ss.P[0] = F[0]; ss.P[1] = F[1];
    g9_sk<<<dim3(16, 8, 2), blk512, 0, stream>>>(ss);
  }
  comb_sig2<<<2048, blk256, 0, stream>>>(F[0], F[1], F[4], (int)(SLOT / 4));
  // 14. out_x = x2 + sig * (h1 @ fWv^T), K=FFD  (split-K x2, partials F0,F3)
  {
    SkArgs sf;
    sf.A = h1; sf.W = fWvB; sf.lda = FFD; sf.ldb = FFD; sf.klen = FFD / 2;
    sf.P[0] = F[0]; sf.P[1] = F[3];
    g9_sk<<<dim3(16, 8, 2), blk512, 0, stream>>>(sf);
  }
  comb_fma2<<<2048, blk256, 0, stream>>>(
      F[0], F[3], F[2], F[4], out_x, (int)(SLOT / 4));
}

// Round 15
// 677.489 us; speedup vs baseline: 1.0349x; 1.0349x over previous
//
#include <hip/hip_runtime.h>
#include <hip/hip_bf16.h>
#include <math.h>

#define BB 2
#define TT 1024
#define CC 2048
#define HH 32
#define KK 64
#define BTROWS (BB*TT)
#define FFD 7168
#define LCH 64
#define NCH (TT/LCH)

typedef unsigned short ushort_t;
typedef __bf16 bf16x8 __attribute__((ext_vector_type(8)));
typedef float f32x4 __attribute__((ext_vector_type(4)));

__device__ __forceinline__ ushort_t f2bf(float f) {
  unsigned int u = __float_as_uint(f);
  u += 0x7fff + ((u >> 16) & 1);
  return (ushort_t)(u >> 16);
}

__device__ __forceinline__ void gload16(const ushort_t* g, ushort_t* l) {
  __builtin_amdgcn_global_load_lds(
      (const __attribute__((address_space(1))) void*)g,
      (__attribute__((address_space(3))) void*)l, 16, 0, 0);
}

#define FMA4(a, s, b) { (a).x = fmaf((s), (b).x, (a).x); (a).y = fmaf((s), (b).y, (a).y); \
                        (a).z = fmaf((s), (b).z, (a).z); (a).w = fmaf((s), (b).w, (a).w); }

// ---------------------------------------------------------------- fp32 -> bf16
__global__ __launch_bounds__(256) void cvt_kernel(
    const float* __restrict__ in, ushort_t* __restrict__ out, int n4) {
  int i = blockIdx.x * 256 + threadIdx.x;
  int stride = gridDim.x * 256;
  for (; i < n4; i += stride) {
    float4 v = ((const float4*)in)[i];
    ushort4 o;
    o.x = f2bf(v.x); o.y = f2bf(v.y); o.z = f2bf(v.z); o.w = f2bf(v.w);
    ((ushort4*)out)[i] = o;
  }
}

// ---------------------------------------------------------------- LayerNorm
__global__ __launch_bounds__(256) void ln_kernel(
    const float* __restrict__ x, const float* __restrict__ w,
    const float* __restrict__ b, float* __restrict__ out,
    float* __restrict__ last_out) {
  int row = blockIdx.x;
  const float* xr = x + (size_t)row * CC;
  float vals[8];
  float sum = 0.f, sq = 0.f;
#pragma unroll
  for (int i = 0; i < 8; ++i) {
    float v = xr[threadIdx.x + 256 * i];
    vals[i] = v; sum += v; sq += v * v;
  }
#pragma unroll
  for (int off = 32; off; off >>= 1) {
    sum += __shfl_xor(sum, off);
    sq  += __shfl_xor(sq, off);
  }
  __shared__ float red[2][4];
  int lane = threadIdx.x & 63, wv = threadIdx.x >> 6;
  if (lane == 0) { red[0][wv] = sum; red[1][wv] = sq; }
  __syncthreads();
  sum = red[0][0] + red[0][1] + red[0][2] + red[0][3];
  sq  = red[1][0] + red[1][1] + red[1][2] + red[1][3];
  float mu = sum * (1.f / CC);
  float var = sq * (1.f / CC) - mu * mu;
  float rs = rsqrtf(var + 1e-5f);
  float* orow = out + (size_t)row * CC;
  int t = row % TT;
  float* lrow = (t == TT - 1) ? (last_out + (size_t)(row / TT) * CC) : nullptr;
#pragma unroll
  for (int i = 0; i < 8; ++i) {
    int c = threadIdx.x + 256 * i;
    float y = (vals[i] - mu) * rs * w[c] + b[c];
    orow[c] = y;
    if (lrow) lrow[c] = y;
  }
}

// ------------------------------------------------- token-shift mix input
__global__ __launch_bounds__(256) void mixin_kernel(
    const float* __restrict__ xn, const float* __restrict__ tms,
    const float* __restrict__ maa_x, float* __restrict__ out) {
  int idx = blockIdx.x * 256 + threadIdx.x;
  int c = idx & (CC - 1);
  int row = idx >> 11;
  int t = row & (TT - 1);
  int b = row >> 10;
  float xv = xn[idx];
  float pv = (t == 0) ? tms[b * CC + c] : xn[idx - CC];
  out[idx] = xv + (pv - xv) * maa_x[c];
}

// ------------------------------------------------- channel-mix shift (bf16 out)
__global__ __launch_bounds__(256) void mix2_kernel(
    const float* __restrict__ xn2, const float* __restrict__ cms,
    const float* __restrict__ fk, const float* __restrict__ fr,
    ushort_t* __restrict__ xk2, ushort_t* __restrict__ xr2) {
  int idx = blockIdx.x * 256 + threadIdx.x;
  int c = idx & (CC - 1);
  int row = idx >> 11;
  int t = row & (TT - 1);
  int b = row >> 10;
  float xv = xn2[idx];
  float pv = (t == 0) ? cms[b * CC + c] : xn2[idx - CC];
  float kf = fk[c], rf = fr[c];
  xk2[idx] = f2bf(pv * kf + xv * (1.f - kf));
  xr2[idx] = f2bf(pv * rf + xv * (1.f - rf));
}

// ------------------------------------------------- split-K skinny fp32 GEMM
__global__ __launch_bounds__(256) void gemm_splitk(
    const float* __restrict__ A, int lda,
    const float* __restrict__ W, int N,
    float* __restrict__ parts, int ntiles, int kslice, int M) {
  __shared__ float As[16][68];
  __shared__ float Ws[16][68];
  const int tid = threadIdx.x;
  const int m0 = blockIdx.x * 64;
  const int n0 = blockIdx.y * 64;
  const int s = blockIdx.z;
  const int kb = s * kslice;
  const int tx = tid & 15, ty = tid >> 4;
  float acc[4][4];
#pragma unroll
  for (int i = 0; i < 4; ++i)
#pragma unroll
    for (int j = 0; j < 4; ++j) acc[i][j] = 0.f;
  for (int k0 = 0; k0 < kslice; k0 += 16) {
    {
      int r = tid >> 2, c = (tid & 3) * 4;
      float4 v = *(const float4*)(A + (size_t)(m0 + r) * lda + kb + k0 + c);
      As[c + 0][r] = v.x; As[c + 1][r] = v.y; As[c + 2][r] = v.z; As[c + 3][r] = v.w;
    }
#pragma unroll
    for (int i = 0; i < 4; ++i) {
      int idx = tid + 256 * i;
      int kr = idx >> 6, nc = idx & 63;
      int n = n0 + nc;
      Ws[kr][nc] = (n < N) ? W[(size_t)(kb + k0 + kr) * N + n] : 0.f;
    }
    __syncthreads();
#pragma unroll
    for (int k = 0; k < 16; ++k) {
      float a[4], w4[4];
#pragma unroll
      for (int i = 0; i < 4; ++i) a[i] = As[k][ty * 4 + i];
#pragma unroll
      for (int j = 0; j < 4; ++j) w4[j] = Ws[k][tx * 4 + j];
#pragma unroll
      for (int i = 0; i < 4; ++i)
#pragma unroll
        for (int j = 0; j < 4; ++j) acc[i][j] = fmaf(a[i], w4[j], acc[i][j]);
    }
    __syncthreads();
  }
  const int NP = ntiles * 64;
  float* pb = parts + (size_t)s * M * NP;
#pragma unroll
  for (int i = 0; i < 4; ++i) {
    int m = m0 + ty * 4 + i;
    float4 v = {acc[i][0], acc[i][1], acc[i][2], acc[i][3]};
    *(float4*)(pb + (size_t)m * NP + n0 + tx * 4) = v;
  }
}

__global__ __launch_bounds__(256) void combine_tanh(
    const float* __restrict__ parts, int NP, int M, int Nreal, int S,
    float* __restrict__ out) {
  int idx = blockIdx.x * 256 + threadIdx.x;
  if (idx >= M * Nreal) return;
  int m = idx / Nreal, n = idx - m * Nreal;
  float acc = 0.f;
  for (int s = 0; s < S; ++s) acc += parts[(size_t)s * M * NP + (size_t)m * NP + n];
  out[idx] = tanhf(acc);
}

// ------------------------------------------------- fp32 tiled GEMM (decay -exp only)
__global__ __launch_bounds__(256) void gemm_negexp(
    const float* __restrict__ A, int lda,
    const float* __restrict__ B, int ldb,
    float* __restrict__ out, int N, int K,
    const float* __restrict__ td) {
  __shared__ float As[16][132];
  __shared__ float Bs[16][132];
  const int tid = threadIdx.x;
  const int tx = tid & 15, ty = tid >> 4;
  const int m0 = blockIdx.y * 128, n0 = blockIdx.x * 128;
  float acc[8][8];
#pragma unroll
  for (int i = 0; i < 8; ++i)
#pragma unroll
    for (int j = 0; j < 8; ++j) acc[i][j] = 0.f;
  for (int k0 = 0; k0 < K; k0 += 16) {
    {
      int r = tid >> 1, c = (tid & 1) * 8;
      const float* src = A + (size_t)(m0 + r) * lda + k0 + c;
      float4 v0 = *(const float4*)src;
      float4 v1 = *(const float4*)(src + 4);
      As[c + 0][r] = v0.x; As[c + 1][r] = v0.y; As[c + 2][r] = v0.z; As[c + 3][r] = v0.w;
      As[c + 4][r] = v1.x; As[c + 5][r] = v1.y; As[c + 6][r] = v1.z; As[c + 7][r] = v1.w;
    }
#pragma unroll
    for (int i = 0; i < 2; ++i) {
      int idx = tid + 256 * i;
      int kk = idx >> 5, nn = (idx & 31) * 4;
      float4 v = *(const float4*)(B + (size_t)(k0 + kk) * ldb + n0 + nn);
      *(float4*)&Bs[kk][nn] = v;
    }
    __syncthreads();
#pragma unroll
    for (int k = 0; k < 16; ++k) {
      float a[8], bb[8];
      *(float4*)&a[0] = *(const float4*)&As[k][ty * 8];
      *(float4*)&a[4] = *(const float4*)&As[k][ty * 8 + 4];
      *(float4*)&bb[0] = *(const float4*)&Bs[k][tx * 8];
      *(float4*)&bb[4] = *(const float4*)&Bs[k][tx * 8 + 4];
#pragma unroll
      for (int i = 0; i < 8; ++i)
#pragma unroll
        for (int j = 0; j < 8; ++j) acc[i][j] = fmaf(a[i], bb[j], acc[i][j]);
    }
    __syncthreads();
  }
#pragma unroll
  for (int i = 0; i < 8; ++i) {
    int row = m0 + ty * 8 + i;
#pragma unroll
    for (int j = 0; j < 8; ++j) {
      int col = n0 + tx * 8 + j;
      out[(size_t)row * N + col] = -expf(td[col] + acc[i][j]);
    }
  }
}

// ------------------------------------------------- mix5: broadcast row-block kernel
struct Mix5Args {
  const float* maa[5];
  float* xw;
  ushort_t* ob[4];   // xk, xv, xr, xg
};

__global__ __launch_bounds__(256) void mix5_gemm(
    const float* __restrict__ hh, const float* __restrict__ w2,
    const float* __restrict__ xn, const float* __restrict__ tms, Mix5Args args) {
  const int f = blockIdx.y;
  const int rb = blockIdx.x;           // 8 rows per block
  const int tid = threadIdx.x;
  __shared__ float hh8[8][32];
  {
    int r = tid >> 5, k = tid & 31;
    hh8[r][k] = hh[(size_t)(rb * 8 + r) * 160 + f * 32 + k];
  }
  __syncthreads();
  const float* maa = args.maa[f];
  const float* w2f = w2 + (size_t)f * 32 * CC;
#pragma unroll
  for (int chunk = 0; chunk < 2; ++chunk) {
    const int col = chunk * 1024 + tid * 4;
    float4 w2v[32];
#pragma unroll
    for (int k = 0; k < 32; ++k)
      w2v[k] = *(const float4*)(w2f + (size_t)k * CC + col);
    const float4 maa4 = *(const float4*)(maa + col);
#pragma unroll
    for (int r = 0; r < 8; ++r) {
      const int row = rb * 8 + r;
      float4 acc = {0.f, 0.f, 0.f, 0.f};
#pragma unroll
      for (int k4 = 0; k4 < 8; ++k4) {
        float4 h = *(const float4*)&hh8[r][k4 * 4];
        FMA4(acc, h.x, w2v[k4 * 4 + 0]);
        FMA4(acc, h.y, w2v[k4 * 4 + 1]);
        FMA4(acc, h.z, w2v[k4 * 4 + 2]);
        FMA4(acc, h.w, w2v[k4 * 4 + 3]);
      }
      const int t = row & (TT - 1);
      const size_t oi = (size_t)row * CC + col;
      float4 xv = *(const float4*)(xn + oi);
      float4 pv;
      if (t == 0) pv = *(const float4*)(tms + (size_t)(row >> 10) * CC + col);
      else        pv = *(const float4*)(xn + oi - CC);
      float4 v;
      v.x = xv.x + (pv.x - xv.x) * (maa4.x + acc.x);
      v.y = xv.y + (pv.y - xv.y) * (maa4.y + acc.y);
      v.z = xv.z + (pv.z - xv.z) * (maa4.z + acc.z);
      v.w = xv.w + (pv.w - xv.w) * (maa4.w + acc.w);
      if (f == 0) {
        *(float4*)(args.xw + oi) = v;
      } else {
        ushort4 o;
        o.x = f2bf(v.x); o.y = f2bf(v.y); o.z = f2bf(v.z); o.w = f2bf(v.w);
        *(ushort4*)(args.ob[f - 1] + oi) = o;
      }
    }
  }
}

// ================================================= g9: 256x128 pipelined MFMA GEMM
template <bool IS_A>
__device__ __forceinline__ void g9_stage(
    char* buf, const ushort_t* g, int ld, int r0, int k0, int tid) {
  constexpr int NJ = IS_A ? 4 : 2;
  char* dst = buf + (IS_A ? 0 : 32768);
#pragma unroll
  for (int j = 0; j < NJ; ++j) {
    int L = j * 8192 + tid * 16;
    int P = L ^ (((L >> 7) & 7) << 4);
    int r = P >> 7, cb = (P & 127) >> 1;
    gload16(g + (size_t)(r0 + r) * ld + k0 + cb, (ushort_t*)(dst + L));
  }
}

__device__ __forceinline__ void g9_core(
    const ushort_t* gA, int lda, const ushort_t* gB, int ldb,
    int m0, int n0, int kstart, int K, char* lds, f32x4 (*acc)[4]) {
  const int tid = threadIdx.x, w = tid >> 6, l = tid & 63;
  const int wr = w >> 1, wc = w & 1;
  const int r16 = l & 15, h16 = (l >> 4) * 16;
  const int NT = K >> 6;
  g9_stage<true>(lds, gA, lda, m0, kstart, tid);
  g9_stage<false>(lds, gB, ldb, n0, kstart, tid);
  g9_stage<true>(lds + 49152, gA, lda, m0, kstart + 64, tid);
  g9_stage<false>(lds + 49152, gB, ldb, n0, kstart + 64, tid);
  int cur = 0;
  for (int t = 0; t < NT; ++t) {
    char* bufc = lds + cur * 49152;
    int nxt = cur + 2; if (nxt >= 3) nxt -= 3;
    char* bufn = lds + nxt * 49152;
    if (t + 1 < NT) asm volatile("s_waitcnt vmcnt(6)" ::: "memory");
    else            asm volatile("s_waitcnt vmcnt(0)" ::: "memory");
    __builtin_amdgcn_s_barrier();
    const bool pf = (t + 2 < NT);
    const int k2 = kstart + (t + 2) * 64;
    // ---- phase kh=0
    {
      bf16x8 a[4], b[4];
#pragma unroll
      for (int mf = 0; mf < 4; ++mf) {
        int row = wr * 64 + mf * 16 + r16;
        int off = h16 ^ ((row & 7) << 4);
        a[mf] = *(const bf16x8*)(bufc + row * 128 + off);
      }
#pragma unroll
      for (int nf = 0; nf < 4; ++nf) {
        int row = wc * 64 + nf * 16 + r16;
        int off = h16 ^ ((row & 7) << 4);
        b[nf] = *(const bf16x8*)(bufc + 32768 + row * 128 + off);
      }
      if (pf) g9_stage<true>(bufn, gA, lda, m0, k2, tid);
      __builtin_amdgcn_s_setprio(1);
#pragma unroll
      for (int mf = 0; mf < 4; ++mf)
#pragma unroll
        for (int nf = 0; nf < 4; ++nf)
          acc[mf][nf] = __builtin_amdgcn_mfma_f32_16x16x32_bf16(a[mf], b[nf], acc[mf][nf], 0, 0, 0);
      __builtin_amdgcn_s_setprio(0);
    }
    // ---- phase kh=1
    {
      bf16x8 a[4], b[4];
#pragma unroll
      for (int mf = 0; mf < 4; ++mf) {
        int row = wr * 64 + mf * 16 + r16;
        int off = (64 + h16) ^ ((row & 7) << 4);
        a[mf] = *(const bf16x8*)(bufc + row * 128 + off);
      }
#pragma unroll
      for (int nf = 0; nf < 4; ++nf) {
        int row = wc * 64 + nf * 16 + r16;
        int off = (64 + h16) ^ ((row & 7) << 4);
        b[nf] = *(const bf16x8*)(bufc + 32768 + row * 128 + off);
      }
      if (pf) g9_stage<false>(bufn, gB, ldb, n0, k2, tid);
      __builtin_amdgcn_s_setprio(1);
#pragma unroll
      for (int mf = 0; mf < 4; ++mf)
#pragma unroll
        for (int nf = 0; nf < 4; ++nf)
          acc[mf][nf] = __builtin_amdgcn_mfma_f32_16x16x32_bf16(a[mf], b[nf], acc[mf][nf], 0, 0, 0);
      __builtin_amdgcn_s_setprio(0);
    }
    cur += 1; if (cur == 3) cur = 0;
  }
}

#define G9_INIT_ACC f32x4 acc[4][4]; \
  _Pragma("unroll") for (int i0 = 0; i0 < 4; ++i0) \
  _Pragma("unroll") for (int i1 = 0; i1 < 4; ++i1) acc[i0][i1] = {0.f, 0.f, 0.f, 0.f};

// r,k,v,g batched: blockIdx.z selects which GEMM
struct RkvgArgs {
  const ushort_t* A[4];
  const ushort_t* W[4];
  float* O[4];
};

__global__ __launch_bounds__(512, 2) void g9_rkvg(RkvgArgs args) {
  __shared__ __align__(16) char lds[147456];
  const int z = blockIdx.z;
  const int m0 = blockIdx.y * 256, n0 = blockIdx.x * 128;
  G9_INIT_ACC
  g9_core(args.A[z], CC, args.W[z], CC, m0, n0, 0, CC, lds, acc);
  const int tid = threadIdx.x, w = tid >> 6, l = tid & 63;
  const int wr = w >> 1, wc = w & 1, r16 = l & 15, q4 = (l >> 4) * 4;
  float* out = args.O[z];
  const bool silu = (z == 3);
#pragma unroll
  for (int mf = 0; mf < 4; ++mf)
#pragma unroll
    for (int nf = 0; nf < 4; ++nf) {
      int col = n0 + wc * 64 + nf * 16 + r16;
#pragma unroll
      for (int j = 0; j < 4; ++j) {
        int row = m0 + wr * 64 + mf * 16 + q4 + j;
        float v = acc[mf][nf][j];
        if (silu) v = v / (1.f + expf(-v));
        out[(size_t)row * CC + col] = v;
      }
    }
}

__global__ __launch_bounds__(512, 2) void g9_relu2(
    const ushort_t* __restrict__ A, int lda,
    const ushort_t* __restrict__ W, int ldb,
    ushort_t* __restrict__ out, int N, int K) {
  __shared__ __align__(16) char lds[147456];
  const int m0 = blockIdx.y * 256, n0 = blockIdx.x * 128;
  G9_INIT_ACC
  g9_core(A, lda, W, ldb, m0, n0, 0, K, lds, acc);
  const int tid = threadIdx.x, w = tid >> 6, l = tid & 63;
  const int wr = w >> 1, wc = w & 1, r16 = l & 15, q4 = (l >> 4) * 4;
#pragma unroll
  for (int mf = 0; mf < 4; ++mf)
#pragma unroll
    for (int nf = 0; nf < 4; ++nf) {
      int col = n0 + wc * 64 + nf * 16 + r16;
#pragma unroll
      for (int j = 0; j < 4; ++j) {
        int row = m0 + wr * 64 + mf * 16 + q4 + j;
        float r_ = fmaxf(acc[mf][nf][j], 0.f);
        out[(size_t)row * N + col] = f2bf(r_ * r_);
      }
    }
}

struct SkArgs {
  const ushort_t* A;
  const ushort_t* W;
  float* P[2];
  int lda, ldb, klen;
};

__global__ __launch_bounds__(512, 2) void g9_sk(SkArgs args) {
  __shared__ __align__(16) char lds[147456];
  const int z = blockIdx.z;
  const int m0 = blockIdx.y * 256, n0 = blockIdx.x * 128;
  G9_INIT_ACC
  g9_core(args.A, args.lda, args.W, args.ldb, m0, n0, z * args.klen, args.klen, lds, acc);
  const int tid = threadIdx.x, w = tid >> 6, l = tid & 63;
  const int wr = w >> 1, wc = w & 1, r16 = l & 15, q4 = (l >> 4) * 4;
  float* out = args.P[z];
#pragma unroll
  for (int mf = 0; mf < 4; ++mf)
#pragma unroll
    for (int nf = 0; nf < 4; ++nf) {
      int col = n0 + wc * 64 + nf * 16 + r16;
#pragma unroll
      for (int j = 0; j < 4; ++j) {
        int row = m0 + wr * 64 + mf * 16 + q4 + j;
        out[(size_t)row * CC + col] = acc[mf][nf][j];
      }
    }
}

// ------------------------------------------------- split-K combines (vectorized)
__global__ __launch_bounds__(256) void comb_add2(
    const float* __restrict__ p0, const float* __restrict__ p1,
    const float* __restrict__ base, float* __restrict__ out, int n4) {
  int i = blockIdx.x * 256 + threadIdx.x;
  int stride = gridDim.x * 256;
  for (; i < n4; i += stride) {
    float4 a = ((const float4*)p0)[i];
    float4 b = ((const float4*)p1)[i];
    float4 c = ((const float4*)base)[i];
    float4 o = {c.x + a.x + b.x, c.y + a.y + b.y, c.z + a.z + b.z, c.w + a.w + b.w};
    ((float4*)out)[i] = o;
  }
}

__global__ __launch_bounds__(256) void comb_sig2(
    const float* __restrict__ p0, const float* __restrict__ p1,
    float* __restrict__ out, int n4) {
  int i = blockIdx.x * 256 + threadIdx.x;
  int stride = gridDim.x * 256;
  for (; i < n4; i += stride) {
    float4 a = ((const float4*)p0)[i];
    float4 b = ((const float4*)p1)[i];
    float4 o;
    o.x = 1.f / (1.f + expf(-(a.x + b.x)));
    o.y = 1.f / (1.f + expf(-(a.y + b.y)));
    o.z = 1.f / (1.f + expf(-(a.z + b.z)));
    o.w = 1.f / (1.f + expf(-(a.w + b.w)));
    ((float4*)out)[i] = o;
  }
}

__global__ __launch_bounds__(256) void comb_fma2(
    const float* __restrict__ p0, const float* __restrict__ p1,
    const float* __restrict__ x2, const float* __restrict__ sig,
    float* __restrict__ out, int n4) {
  int i = blockIdx.x * 256 + threadIdx.x;
  int stride = gridDim.x * 256;
  for (; i < n4; i += stride) {
    float4 a = ((const float4*)p0)[i];
    float4 b = ((const float4*)p1)[i];
    float4 xx = ((const float4*)x2)[i];
    float4 ss = ((const float4*)sig)[i];
    float4 o;
    o.x = fmaf(ss.x, a.x + b.x, xx.x);
    o.y = fmaf(ss.y, a.y + b.y, xx.y);
    o.z = fmaf(ss.z, a.z + b.z, xx.z);
    o.w = fmaf(ss.w, a.w + b.w, xx.w);
    ((float4*)out)[i] = o;
  }
}

// ================================================= chunked WKV scan
__global__ __launch_bounds__(256) void wkv_chunk1(
    const float* __restrict__ r, const float* __restrict__ k,
    const float* __restrict__ v, const float* __restrict__ w,
    const float* __restrict__ u,
    float* __restrict__ rtG, float* __restrict__ Pg,
    float* __restrict__ dg, float* __restrict__ o_intra) {
  __shared__ __align__(16) float lds[4 * 4160];
  float* Ech = lds;                 // [64][64] inclusive cumsum C
  float* Ach = lds;                 // [64][65] A, aliases Ech after stage 2
  float* rtl = lds + 4160;          // [64][65]
  float* ktl = lds + 2 * 4160;      // [64][65]
  float* Vl  = lds + 3 * 4160;      // [64][65]
  __shared__ float Dl[64], dl[64];
  const int c = blockIdx.x, bh = blockIdx.y;
  const int b = bh >> 5, h = bh & 31;
  const int tid = threadIdx.x;
  const size_t base = (size_t)b * TT * CC + (size_t)(c * LCH) * CC + h * KK;
  for (int i = 0; i < 16; ++i) {
    int e = tid + 256 * i;
    int row = e >> 6, col = e & 63;
    size_t g = base + (size_t)row * CC + col;
    rtl[row * 65 + col] = r[g];
    ktl[row * 65 + col] = k[g];
    Vl[row * 65 + col] = v[g];
  }
  if (tid < 64) {
    float cum = 0.f;
#pragma unroll 8
    for (int i = 0; i < 64; ++i) {
      cum += w[base + (size_t)i * CC + tid];
      Ech[i * 64 + tid] = cum;
    }
    float dd = expf(cum);
    dl[tid] = dd;
    dg[(size_t)(bh * NCH + c) * 64 + tid] = dd;
  }
  __syncthreads();
  {
    const int g = tid >> 6, kk = tid & 63;
    const float uk = u[h * KK + kk];
    for (int i = 0; i < 16; ++i) {
      int t = i * 4 + g;
      float Cv = Ech[t * 64 + kk];
      float Ev = (t == 0) ? 0.f : Ech[(t - 1) * 64 + kk];
      float rraw = rtl[t * 65 + kk];
      float kraw = ktl[t * 65 + kk];
      float rtv = rraw * expf(Ev);
      float ktv = kraw * expf(-Cv);
      rtl[t * 65 + kk] = rtv;
      ktl[t * 65 + kk] = ktv;
      rtG[((size_t)(bh * NCH + c) * 64 + t) * 64 + kk] = rtv;
      float prod = rraw * uk * kraw;
#pragma unroll
      for (int off = 32; off; off >>= 1) prod += __shfl_xor(prod, off);
      if (kk == 0) Dl[t] = prod;
    }
  }
  __syncthreads();
  {
    const int ti = tid >> 4, tj = tid & 15;
    float a4[4][4];
#pragma unroll
    for (int a = 0; a < 4; ++a)
#pragma unroll
      for (int q = 0; q < 4; ++q) a4[a][q] = 0.f;
    for (int kk = 0; kk < 64; ++kk) {
      float ra[4], kb[4];
#pragma unroll
      for (int a = 0; a < 4; ++a) ra[a] = rtl[(4 * ti + a) * 65 + kk];
#pragma unroll
      for (int q = 0; q < 4; ++q) kb[q] = ktl[(4 * tj + q) * 65 + kk];
#pragma unroll
      for (int a = 0; a < 4; ++a)
#pragma unroll
        for (int q = 0; q < 4; ++q) a4[a][q] = fmaf(ra[a], kb[q], a4[a][q]);
    }
#pragma unroll
    for (int a = 0; a < 4; ++a) {
      int i = 4 * ti + a;
#pragma unroll
      for (int q = 0; q < 4; ++q) {
        int j = 4 * tj + q;
        Ach[i * 65 + j] = (j < i) ? a4[a][q] : (j == i ? Dl[i] : 0.f);
      }
    }
  }
  __syncthreads();
  {
    const int tr = tid >> 4, tv = tid & 15;
    float o4[4][4], p4[4][4];
#pragma unroll
    for (int a = 0; a < 4; ++a)
#pragma unroll
      for (int q = 0; q < 4; ++q) { o4[a][q] = 0.f; p4[a][q] = 0.f; }
    for (int j = 0; j < 64; ++j) {
      float av[4], kv4[4], vv[4];
#pragma unroll
      for (int a = 0; a < 4; ++a) av[a] = Ach[(4 * tr + a) * 65 + j];
#pragma unroll
      for (int a = 0; a < 4; ++a) kv4[a] = ktl[j * 65 + 4 * tr + a];
#pragma unroll
      for (int q = 0; q < 4; ++q) vv[q] = Vl[j * 65 + 4 * tv + q];
#pragma unroll
      for (int a = 0; a < 4; ++a)
#pragma unroll
        for (int q = 0; q < 4; ++q) {
          o4[a][q] = fmaf(av[a], vv[q], o4[a][q]);
          p4[a][q] = fmaf(kv4[a], vv[q], p4[a][q]);
        }
    }
#pragma unroll
    for (int a = 0; a < 4; ++a) {
      int i = 4 * tr + a;
      float4 ov = {o4[a][0], o4[a][1], o4[a][2], o4[a][3]};
      *(float4*)(o_intra + base + (size_t)i * CC + 4 * tv) = ov;
    }
#pragma unroll
    for (int a = 0; a < 4; ++a) {
      int kk2 = 4 * tr + a;
      float dd = dl[kk2];
      float4 pv = {p4[a][0] * dd, p4[a][1] * dd, p4[a][2] * dd, p4[a][3] * dd};
      *(float4*)(Pg + ((size_t)(bh * NCH + c) * 64 + kk2) * 64 + 4 * tv) = pv;
    }
  }
}

__global__ __launch_bounds__(256) void wkv_chain(
    const float* __restrict__ P, const float* __restrict__ d,
    const float* __restrict__ s0, float* __restrict__ s_starts,
    float* __restrict__ s_out) {
  const int bh = blockIdx.x;
  const int tid = threadIdx.x;
  float s[16];
#pragma unroll
  for (int m = 0; m < 16; ++m) s[m] = s0[(size_t)bh * 4096 + tid + 256 * m];
  for (int c = 0; c < NCH; ++c) {
    size_t cb = (size_t)(bh * NCH + c) * 4096;
#pragma unroll
    for (int m = 0; m < 16; ++m) {
      int idx = tid + 256 * m;
      s_starts[cb + idx] = s[m];
      float dd = d[(size_t)(bh * NCH + c) * 64 + (idx >> 6)];
      s[m] = fmaf(dd, s[m], P[cb + idx]);
    }
  }
#pragma unroll
  for (int m = 0; m < 16; ++m) s_out[(size_t)bh * 4096 + tid + 256 * m] = s[m];
}

__global__ __launch_bounds__(256) void wkv_chunk2(
    const float* __restrict__ rtG, const float* __restrict__ s_starts,
    const float* __restrict__ o_intra, const float* __restrict__ g,
    const float* __restrict__ lnw, const float* __restrict__ lnb,
    ushort_t* __restrict__ ym) {
  __shared__ __align__(16) float lds[3 * 4160];
  float* rtl = lds;             // [64][65] t x k
  float* sl  = lds + 4160;      // [64][65] k x v
  float* ol  = lds + 2 * 4160;  // [64][65] t x v
  __shared__ float mul[64], rsl[64];
  const int c = blockIdx.x, bh = blockIdx.y;
  const int b = bh >> 5, h = bh & 31;
  const int tid = threadIdx.x;
  const size_t base = (size_t)b * TT * CC + (size_t)(c * LCH) * CC + h * KK;
  const size_t cb = (size_t)(bh * NCH + c) * 4096;
  for (int i = 0; i < 16; ++i) {
    int e = tid + 256 * i;
    int row = e >> 6, col = e & 63;
    rtl[row * 65 + col] = rtG[cb + e];
    sl[row * 65 + col] = s_starts[cb + e];
  }
  __syncthreads();
  {
    const int tr = tid >> 4, tv = tid & 15;
    float o4[4][4];
#pragma unroll
    for (int a = 0; a < 4; ++a)
#pragma unroll
      for (int q = 0; q < 4; ++q) o4[a][q] = 0.f;
    for (int kk = 0; kk < 64; ++kk) {
      float ra[4], sv[4];
#pragma unroll
      for (int a = 0; a < 4; ++a) ra[a] = rtl[(4 * tr + a) * 65 + kk];
#pragma unroll
      for (int q = 0; q < 4; ++q) sv[q] = sl[kk * 65 + 4 * tv + q];
#pragma unroll
      for (int a = 0; a < 4; ++a)
#pragma unroll
        for (int q = 0; q < 4; ++q) o4[a][q] = fmaf(ra[a], sv[q], o4[a][q]);
    }
#pragma unroll
    for (int a = 0; a < 4; ++a) {
      int i = 4 * tr + a;
      float4 oi = *(const float4*)(o_intra + base + (size_t)i * CC + 4 * tv);
      ol[i * 65 + 4 * tv + 0] = o4[a][0] + oi.x;
      ol[i * 65 + 4 * tv + 1] = o4[a][1] + oi.y;
      ol[i * 65 + 4 * tv + 2] = o4[a][2] + oi.z;
      ol[i * 65 + 4 * tv + 3] = o4[a][3] + oi.w;
    }
  }
  __syncthreads();
  {
    int row = tid >> 2, q = tid & 3;
    float sum = 0.f, sq = 0.f;
#pragma unroll
    for (int j = 0; j < 16; ++j) {
      float val = ol[row * 65 + q * 16 + j];
      sum += val; sq += val * val;
    }
    sum += __shfl_xor(sum, 1); sq += __shfl_xor(sq, 1);
    sum += __shfl_xor(sum, 2); sq += __shfl_xor(sq, 2);
    if (q == 0) {
      float mu = sum * (1.f / 64.f);
      float var = sq * (1.f / 64.f) - mu * mu;
      mul[row] = mu;
      rsl[row] = rsqrtf(var + 6.4e-4f);
    }
  }
  __syncthreads();
  for (int i = 0; i < 16; ++i) {
    int e = tid + 256 * i;
    int row = e >> 6, col = e & 63;
    float val = (ol[row * 65 + col] - mul[row]) * rsl[row];
    val = val * lnw[h * KK + col] + lnb[h * KK + col];
    size_t gi = base + (size_t)row * CC + col;
    ym[gi] = f2bf(val * g[gi]);
  }
}

// =================================================================== launch
extern "C" void kernel_launch(void* const* d_in, const int* in_sizes, int n_in,
                              void* d_out, int out_size, void* d_ws, size_t ws_size,
                              hipStream_t stream) {
  const float* x    = (const float*)d_in[0];
  const float* tms  = (const float*)d_in[1];
  const float* cms  = (const float*)d_in[2];
  const float* tmstate = (const float*)d_in[3];
  const float* ln1_w = (const float*)d_in[4];
  const float* ln1_b = (const float*)d_in[5];
  const float* ln2_w = (const float*)d_in[6];
  const float* ln2_b = (const float*)d_in[7];
  const float* maa_x = (const float*)d_in[8];
  const float* maa_w = (const float*)d_in[9];
  const float* maa_k = (const float*)d_in[10];
  const float* maa_v = (const float*)d_in[11];
  const float* maa_r = (const float*)d_in[12];
  const float* maa_g = (const float*)d_in[13];
  const float* maa_w1 = (const float*)d_in[14];
  const float* maa_w2 = (const float*)d_in[15];
  const float* td    = (const float*)d_in[16];
  const float* td_w1 = (const float*)d_in[17];
  const float* td_w2 = (const float*)d_in[18];
  const float* u     = (const float*)d_in[19];
  const float* Wr    = (const float*)d_in[20];
  const float* Wk    = (const float*)d_in[21];
  const float* Wv    = (const float*)d_in[22];
  const float* Wg    = (const float*)d_in[23];
  const float* Wo    = (const float*)d_in[24];
  const float* lnx_w = (const float*)d_in[25];
  const float* lnx_b = (const float*)d_in[26];
  const float* fmk   = (const float*)d_in[27];
  const float* fmr   = (const float*)d_in[28];
  const float* fWk   = (const float*)d_in[29];
  const float* fWr   = (const float*)d_in[30];
  const float* fWv   = (const float*)d_in[31];
  (void)in_sizes; (void)n_in; (void)out_size;

  const size_t SLOT = (size_t)BTROWS * CC;   // 4M elements
  float* F[7];
  for (int i = 0; i < 7; ++i) F[i] = (float*)d_ws + i * SLOT;
  ushort_t* B0 = (ushort_t*)((float*)d_ws + 7 * SLOT);
  ushort_t* B1 = B0 + SLOT;
  ushort_t* B2 = B1 + SLOT;
  ushort_t* B3 = B2 + SLOT;
  ushort_t* WBIG = B3 + SLOT;                    // 4*CC*CC; later fWkB
  ushort_t* WrB = WBIG;
  ushort_t* WkB = WrB + (size_t)CC * CC;
  ushort_t* WvB = WkB + (size_t)CC * CC;
  ushort_t* WgB = WvB + (size_t)CC * CC;
  ushort_t* WoB = WBIG + (size_t)4 * CC * CC;    // CC*CC; later fWrB
  ushort_t* fWvB = WoB + (size_t)CC * CC;        // CC*FFD
  float* hh  = (float*)(fWvB + (size_t)CC * FFD);
  float* tmpd = hh + (size_t)BTROWS * 160;
  size_t need = (size_t)((char*)(tmpd + (size_t)BTROWS * 64) - (char*)d_ws);
  if (ws_size < need) return;
  ushort_t* fWkB = WBIG;
  ushort_t* fWrB = WoB;
  ushort_t* h1   = (ushort_t*)F[5];              // spans F5+F6

  // scan scratch (reuses dead regions)
  float* rtG = F[1];
  float* o_intra = F[0];
  float* s_starts = (float*)B0;      // spans B0,B1
  float* Pg = (float*)B2;            // spans B2,B3
  float* dbuf = (float*)(WBIG + (size_t)FFD * CC);
  ushort_t* ym = B3;

  // split-K parts
  float* partsW1 = F[4];
  float* partsTD = F[5];

  float* out_x    = (float*)d_out;
  float* out_shift = out_x + (size_t)BB * TT * CC;
  float* out_cm   = out_shift + (size_t)BB * CC;
  float* out_wkv  = out_cm + (size_t)BB * CC;

  const dim3 blk256(256);
  const dim3 blk512(512);

  // 0. weight conversions
  cvt_kernel<<<2048, blk256, 0, stream>>>(Wr, WrB, CC * CC / 4);
  cvt_kernel<<<2048, blk256, 0, stream>>>(Wk, WkB, CC * CC / 4);
  cvt_kernel<<<2048, blk256, 0, stream>>>(Wv, WvB, CC * CC / 4);
  cvt_kernel<<<2048, blk256, 0, stream>>>(Wg, WgB, CC * CC / 4);
  cvt_kernel<<<2048, blk256, 0, stream>>>(Wo, WoB, CC * CC / 4);
  cvt_kernel<<<2048, blk256, 0, stream>>>(fWv, fWvB, CC * FFD / 4);

  // 1. xn = LN(x) -> F0, new_shift
  ln_kernel<<<BTROWS, blk256, 0, stream>>>(x, ln1_w, ln1_b, F[0], out_shift);
  // 2. mixin -> F3
  mixin_kernel<<<(BTROWS * CC) / 256, blk256, 0, stream>>>(F[0], tms, maa_x, F[3]);
  // 3. hh = tanh(mixin @ maa_w1)  (split-K)
  gemm_splitk<<<dim3(BTROWS / 64, 3, 8), blk256, 0, stream>>>(
      F[3], CC, maa_w1, 160, partsW1, 3, CC / 8, BTROWS);
  combine_tanh<<<(BTROWS * 160 + 255) / 256, blk256, 0, stream>>>(
      partsW1, 192, BTROWS, 160, 8, hh);
  // 4. mix5: xw->F1 (f32), xk->B1, xv->B2, xr->B3, xg->B0 (bf16)
  {
    Mix5Args ma;
    ma.maa[0] = maa_w; ma.maa[1] = maa_k; ma.maa[2] = maa_v; ma.maa[3] = maa_r; ma.maa[4] = maa_g;
    ma.xw = F[1];
    ma.ob[0] = B1; ma.ob[1] = B2; ma.ob[2] = B3; ma.ob[3] = B0;
    mix5_gemm<<<dim3(BTROWS / 8, 5), blk256, 0, stream>>>(hh, maa_w2, F[0], tms, ma);
  }
  // 5. decay: tmpd = tanh(xw @ td_w1) (split-K); w = -exp(td + tmpd @ td_w2) -> F2
  gemm_splitk<<<dim3(BTROWS / 64, 1, 8), blk256, 0, stream>>>(
      F[1], CC, td_w1, 64, partsTD, 1, CC / 8, BTROWS);
  combine_tanh<<<(BTROWS * 64 + 255) / 256, blk256, 0, stream>>>(
      partsTD, 64, BTROWS, 64, 8, tmpd);
  gemm_negexp<<<dim3(16, 16), blk256, 0, stream>>>(tmpd, 64, td_w2, CC, F[2], CC, 64, td);
  // 6. r,k,v,g (g9 256x128, z-batched): r->F3, k->F4, v->F5, g->F6(silu)
  {
    RkvgArgs ra;
    ra.A[0] = B3; ra.A[1] = B1; ra.A[2] = B2; ra.A[3] = B0;
    ra.W[0] = WrB; ra.W[1] = WkB; ra.W[2] = WvB; ra.W[3] = WgB;
    ra.O[0] = F[3]; ra.O[1] = F[4]; ra.O[2] = F[5]; ra.O[3] = F[6];
    g9_rkvg<<<dim3(16, 8, 4), blk512, 0, stream>>>(ra);
  }
  // convert fWk into WBIG (Wr..Wg dead after rkvg)
  cvt_kernel<<<2048, blk256, 0, stream>>>(fWk, fWkB, FFD * CC / 4);
  // 7. chunked WKV scan
  wkv_chunk1<<<dim3(NCH, BB * HH), blk256, 0, stream>>>(
      F[3], F[4], F[5], F[2], u, rtG, Pg, dbuf, o_intra);
  wkv_chain<<<BB * HH, blk256, 0, stream>>>(Pg, dbuf, tmstate, s_starts, out_wkv);
  wkv_chunk2<<<dim3(NCH, BB * HH), blk256, 0, stream>>>(
      rtG, s_starts, o_intra, F[6], lnx_w, lnx_b, ym);
  // 9. x2 = x + ym @ Wo^T -> F2  (split-K x2, partials F0,F1; 256 blocks = 1/CU)
  {
    SkArgs sa;
    sa.A = ym; sa.W = WoB; sa.lda = CC; sa.ldb = CC; sa.klen = CC / 2;
    sa.P[0] = F[0]; sa.P[1] = F[1];
    g9_sk<<<dim3(16, 8, 2), blk512, 0, stream>>>(sa);
  }
  comb_add2<<<2048, blk256, 0, stream>>>(F[0], F[1], x, F[2], (int)(SLOT / 4));
  // convert fWr into WoB region (Wo dead)
  cvt_kernel<<<2048, blk256, 0, stream>>>(fWr, fWrB, CC * CC / 4);
  // 10. xn2 = LN2(x2) -> F1, new_cm
  ln_kernel<<<BTROWS, blk256, 0, stream>>>(F[2], ln2_w, ln2_b, F[1], out_cm);
  // 11. xk2 -> B1, xr2 -> B2 (bf16)
  mix2_kernel<<<(BTROWS * CC) / 256, blk256, 0, stream>>>(F[1], cms, fmk, fmr, B1, B2);
  // 12. h1 = relu(xk2 @ fWk^T)^2 -> bf16, N=FFD
  g9_relu2<<<dim3(FFD / 128, 8), blk512, 0, stream>>>(B1, CC, fWkB, CC, h1, FFD, CC);
  // 13. sig = sigmoid(xr2 @ fWr^T) -> F4  (split-K x2, partials F0,F1)
  {
    SkArgs ss;
    ss.A = B2; ss.W = fWrB; ss.lda = CC; ss.ldb = CC; ss.klen = CC / 2;
    ss.P[0] = F[0]; ss.P[1] = F[1];
    g9_sk<<<dim3(16, 8, 2), blk512, 0, stream>>>(ss);
  }
  comb_sig2<<<2048, blk256, 0, stream>>>(F[0], F[1], F[4], (int)(SLOT / 4));
  // 14. out_x = x2 + sig * (h1 @ fWv^T), K=FFD  (split-K x2, partials F0,F3)
  {
    SkArgs sf;
    sf.A = h1; sf.W = fWvB; sf.lda = FFD; sf.ldb = FFD; sf.klen = FFD / 2;
    sf.P[0] = F[0]; sf.P[1] = F[3];
    g9_sk<<<dim3(16, 8, 2), blk512, 0, stream>>>(sf);
  }
  comb_fma2<<<2048, blk256, 0, stream>>>(
      F[0], F[3], F[2], F[4], out_x, (int)(SLOT / 4));
}